// Round 2
// baseline (863.195 us; speedup 1.0000x reference)
//
#include <hip/hip_runtime.h>

// ActionThenNodePolicy — MI355X fp32, round 2.
// 1 block (256 thr) per graph. Phase A: k-chunked LDS x LDS register-tiled
// GEMM (4 nodes x 7 outputs per thread), both operands DMA-staged via
// global_load_lds with XOR-swizzled source. Phase B: in-block softmaxes.

#define NG   2048
#define NEGV -1000000000.0f
#define EPSV 1e-20f

typedef const __attribute__((address_space(1))) void g_void;
typedef __attribute__((address_space(3))) void l_void;

struct WS {
  int flag;          // 1 => mask elements are 4-byte, 0 => 1-byte bool
  int pad[63];
  float Wall[112 * 256]; // 0: W_node; 1..32: W_agn; 33..64: W_nga; 65..96: 0.5*(Wq[a]+Wq[a+32]); 97..111: 0
};

__global__ void prep_kernel(const unsigned char* __restrict__ atm,
                            const float* __restrict__ Wn,
                            const float* __restrict__ Wagn,
                            const float* __restrict__ Wnga,
                            const float* __restrict__ Wq,
                            WS* __restrict__ ws)
{
  const int t = threadIdx.x;
  const int b = blockIdx.x;
  if (b == 0) {
    __shared__ int s_off, s_max;
    if (t == 0) { s_off = 0; s_max = 0; }
    __syncthreads();
    int loc_off = 0, loc_max = 0;
    for (int i = t; i < 4096; i += 256) {
      int v = atm[i];
      loc_max = max(loc_max, v);
      if ((i & 3) != 0 && v != 0) loc_off = 1;
    }
    if (loc_off) atomicOr(&s_off, 1);
    atomicMax(&s_max, loc_max);
    __syncthreads();
    if (t == 0) ws->flag = (s_max > 1) ? 1 : (s_off ? 0 : 1);
  }
  for (int e = b * 256 + t; e < 112 * 256; e += 64 * 256) {
    int ro = e >> 8, k = e & 255;
    float w = 0.f;
    if (ro == 0)       w = Wn[k];
    else if (ro < 33)  w = Wagn[(ro - 1) * 256 + k];
    else if (ro < 65)  w = Wnga[(ro - 33) * 256 + k];
    else if (ro < 97)  w = 0.5f * (Wq[(ro - 65) * 256 + k] + Wq[(ro - 33) * 256 + k]);
    ws->Wall[e] = w;
  }
}

__global__ __launch_bounds__(256, 5) void policy_kernel(
    const int* __restrict__ a_in,
    const float* __restrict__ values,
    const void* __restrict__ atm,
    const void* __restrict__ aam,
    const WS* __restrict__ ws,
    float* __restrict__ out)
{
  // Phase A: Vbuf (float4[64][8], 8KB) at sm[0]; Wbuf (float4[112][8], 14KB) at sm[2048].
  // Phase B (aliases): Out[112][65] at sm[0]; pn/papt/pa/segq/hn after.
  __shared__ float sm[7696];
  float4* vb4 = (float4*)sm;
  float4* wb4 = (float4*)(sm + 2048);

  const int t  = threadIdx.x;
  const int g  = blockIdx.x;
  const int wv = t >> 6;

  const int nb  = t & 15;   // nodes {nb, nb+16, nb+32, nb+48}
  const int og  = t >> 4;   // outputs {og*7 .. og*7+6}
  const int swz = nb & 7;   // (nb+16i)&7 == nb&7

  int rb[7], rs[7];
  #pragma unroll
  for (int o = 0; o < 7; ++o) { int row = og * 7 + o; rb[o] = row << 3; rs[o] = row & 7; }

  float acc[4][7];
  #pragma unroll
  for (int i = 0; i < 4; ++i)
    #pragma unroll
    for (int o = 0; o < 7; ++o) acc[i][o] = 0.f;

  const float* vsrc = values + (size_t)g * 16384;
  const float* wsrc = ws->Wall;

  for (int kt = 0; kt < 8; ++kt) {
    if (kt) __syncthreads();            // prev chunk's reads complete
    // ---- stage V chunk: dest f4 f = n*8+k4s holds V[n][kt*32 + (k4s^(n&7))*4] ----
    #pragma unroll
    for (int i = 0; i < 2; ++i) {
      int f = (i << 8) + t;
      int n_ = f >> 3, k4s = f & 7;
      const float* src = vsrc + n_ * 256 + (kt << 5) + ((k4s ^ (n_ & 7)) << 2);
      l_void* dst = (l_void*)(vb4 + (i << 8) + (wv << 6));
      __builtin_amdgcn_global_load_lds((g_void*)src, dst, 16, 0, 0);
    }
    // ---- stage W chunk: dest f4 f = row*8+k4s holds W[row][kt*32 + (k4s^(row&7))*4] ----
    #pragma unroll
    for (int i = 0; i < 4; ++i) {
      int f = (i << 8) + t;
      if (f < 896) {
        int row = f >> 3, k4s = f & 7;
        const float* src = wsrc + row * 256 + (kt << 5) + ((k4s ^ (row & 7)) << 2);
        l_void* dst = (l_void*)(wb4 + (i << 8) + (wv << 6));
        __builtin_amdgcn_global_load_lds((g_void*)src, dst, 16, 0, 0);
      }
    }
    __syncthreads();                    // staging landed (vmcnt drained before barrier)

    // ---- compute: 8 k4-steps, 112 FMA each ----
    #pragma unroll
    for (int k4 = 0; k4 < 8; ++k4) {
      float4 v0 = vb4[((nb      ) << 3) + (k4 ^ swz)];
      float4 v1 = vb4[((nb + 16) << 3) + (k4 ^ swz)];
      float4 v2 = vb4[((nb + 32) << 3) + (k4 ^ swz)];
      float4 v3 = vb4[((nb + 48) << 3) + (k4 ^ swz)];
      #pragma unroll
      for (int o = 0; o < 7; ++o) {
        float4 w = wb4[rb[o] + (k4 ^ rs[o])];
        acc[0][o] = fmaf(v0.w, w.w, fmaf(v0.z, w.z, fmaf(v0.y, w.y, fmaf(v0.x, w.x, acc[0][o]))));
        acc[1][o] = fmaf(v1.w, w.w, fmaf(v1.z, w.z, fmaf(v1.y, w.y, fmaf(v1.x, w.x, acc[1][o]))));
        acc[2][o] = fmaf(v2.w, w.w, fmaf(v2.z, w.z, fmaf(v2.y, w.y, fmaf(v2.x, w.x, acc[2][o]))));
        acc[3][o] = fmaf(v3.w, w.w, fmaf(v3.z, w.z, fmaf(v3.y, w.y, fmaf(v3.x, w.x, acc[3][o]))));
      }
    }
  }
  __syncthreads();   // all LDS reads done; safe to alias with Out

  // ---- write results: Out[row][n], row-major stride 65 ----
  float* Out = sm;
  #pragma unroll
  for (int o = 0; o < 7; ++o) {
    int row = og * 7 + o;
    if (row < 97) {
      #pragma unroll
      for (int i = 0; i < 4; ++i) Out[row * 65 + nb + (i << 4)] = acc[i][o];
    }
  }
  __syncthreads();

  float* pn   = sm + 7280;  // 64
  float* papt = sm + 7344;  // 8*32
  float* pa   = sm + 7600;  // 32
  float* segq = sm + 7632;  // 32
  float* hn   = sm + 7664;  // 32

  const int f4 = ws->flag;
  const size_t mb = (size_t)g * 2048;
  auto mget = [&](const void* p, size_t idx) -> bool {
    return f4 ? (((const int*)p)[idx] != 0)
              : (((const unsigned char*)p)[idx] != 0);
  };

  // ---- B1: p_n = softmax over 64 node logits (wave 0) ----
  if (t < 64) {
    float x = Out[0 * 65 + t];
    float m = x;
    #pragma unroll
    for (int s = 32; s > 0; s >>= 1) m = fmaxf(m, __shfl_xor(m, s));
    float z = __expf(x - m);
    float su = z;
    #pragma unroll
    for (int s = 32; s > 0; s >>= 1) su += __shfl_xor(su, s);
    pn[t] = z / su;
  }
  __syncthreads();

  // ---- B2: p_a_given_n row softmax (32-lane groups), accumulate p_a partials ----
  {
    const int aA = t & 31, grp = t >> 5;
    float part = 0.f;
    for (int j = 0; j < 8; ++j) {
      int nn = grp * 8 + j;
      bool mk = mget(atm, mb + (size_t)nn * 32 + aA);
      float l = mk ? Out[(1 + aA) * 65 + nn] : NEGV;
      float m = l;
      #pragma unroll
      for (int s = 16; s > 0; s >>= 1) m = fmaxf(m, __shfl_xor(m, s));
      float z = __expf(l - m);
      float su = z;
      #pragma unroll
      for (int s = 16; s > 0; s >>= 1) su += __shfl_xor(su, s);
      part += pn[nn] * (z / su);
    }
    papt[grp * 32 + aA] = part;
  }

  // ---- B3: p_n__a segment softmax per action column (8-lane groups x 8 nodes) ----
  {
    const int a2 = t >> 3, r = t & 7;
    float lj[8];
    float m = -3.4e38f;
    #pragma unroll
    for (int j = 0; j < 8; ++j) {
      int nn = r * 8 + j;
      size_t mi = mb + (size_t)nn * 32 + a2;
      bool mk = mget(atm, mi) && mget(aam, mi);
      float l = mk ? Out[(33 + a2) * 65 + nn] : NEGV;
      lj[j] = l;
      m = fmaxf(m, l);
    }
    #pragma unroll
    for (int s = 4; s > 0; s >>= 1) m = fmaxf(m, __shfl_xor(m, s));
    float su = 0.f;
    #pragma unroll
    for (int j = 0; j < 8; ++j) { lj[j] = __expf(lj[j] - m); su += lj[j]; }
    #pragma unroll
    for (int s = 4; s > 0; s >>= 1) su += __shfl_xor(su, s);
    float inv = 1.f / su;
    float hq = 0.f, pq = 0.f;
    #pragma unroll
    for (int j = 0; j < 8; ++j) {
      int nn = r * 8 + j;
      float p = lj[j] * inv;
      Out[(33 + a2) * 65 + nn] = p;                 // p_n__a in place
      hq -= p * __logf(p + EPSV);
      pq = fmaf(p, Out[(65 + a2) * 65 + nn], pq);   // q row
    }
    #pragma unroll
    for (int s = 4; s > 0; s >>= 1) { hq += __shfl_xor(hq, s); pq += __shfl_xor(pq, s); }
    if (r == 0) { segq[a2] = pq; hn[a2] = hq; }
  }
  __syncthreads();

  // ---- B4: finalize ----
  if (t < 32) {
    float s0 = 0.f;
    #pragma unroll
    for (int gq = 0; gq < 8; ++gq) s0 += papt[gq * 32 + t];
    pa[t] = s0;
    out[6144 + g * 32 + t] = s0;  // p_a
    float v1 = s0 * segq[t];
    float e1 = -s0 * __logf(s0 + EPSV);
    float e2 = s0 * hn[t];
    #pragma unroll
    for (int s = 16; s > 0; s >>= 1) {
      v1 += __shfl_xor(v1, s);
      e1 += __shfl_xor(e1, s);
      e2 += __shfl_xor(e2, s);
    }
    if (t == 0) {
      out[4096 + g] = v1;       // value
      out[2048 + g] = e1 + e2;  // entropy
      int act = a_in[g * 2 + 0];
      int anl = a_in[g * 2 + 1] - g * 64;
      out[g] = __logf(pa[act] + EPSV) + __logf(Out[(33 + act) * 65 + anl] + EPSV);
    }
  }
  const size_t ob = 71680 + (size_t)g * 2048;
  #pragma unroll
  for (int i = 0; i < 8; ++i) {
    int e = t + (i << 8);
    out[ob + e] = Out[(33 + (e & 31)) * 65 + (e >> 5)];
  }
}

extern "C" void kernel_launch(void* const* d_in, const int* in_sizes, int n_in,
                              void* d_out, int out_size, void* d_ws, size_t ws_size,
                              hipStream_t stream)
{
  const int*   a_in   = (const int*)d_in[0];
  const float* values = (const float*)d_in[1];
  const void*  atm    = d_in[3];
  const void*  aam    = d_in[4];
  const float* Wn     = (const float*)d_in[6];
  const float* Wagn   = (const float*)d_in[7];
  const float* Wnga   = (const float*)d_in[8];
  const float* Wq     = (const float*)d_in[9];
  WS*    ws  = (WS*)d_ws;
  float* out = (float*)d_out;

  hipLaunchKernelGGL(prep_kernel, dim3(64), dim3(256), 0, stream,
                     (const unsigned char*)atm, Wn, Wagn, Wnga, Wq, ws);
  hipLaunchKernelGGL(policy_kernel, dim3(NG), dim3(256), 0, stream,
                     a_in, values, atm, aam, ws, out);
}

// Round 4
// 368.204 us; speedup vs baseline: 2.3443x; 2.3443x over previous
//
#include <hip/hip_runtime.h>

// ActionThenNodePolicy — MI355X fp32, round 3 (resubmit; round-3 bench was an
// infra failure). 1 block (256 thr) per graph. Lane = node, wave = row-group
// (25/24/24/24 of 97). W read via wave-uniform s_load (L2-resident), V via
// double-buffered global_load_lds chunks with XOR-swizzled source.

#define NG   2048
#define NEGV -1000000000.0f
#define EPSV 1e-20f

typedef const __attribute__((address_space(1))) void g_void;
typedef __attribute__((address_space(3))) void l_void;

struct WS {
  int flag;          // 1 => mask elements are 4-byte, 0 => 1-byte bool
  int pad[63];
  float Wall[112 * 256]; // 0: W_node; 1..32: W_agn; 33..64: W_nga; 65..96: 0.5*(Wq[a]+Wq[a+32])
};

__global__ void prep_kernel(const unsigned char* __restrict__ atm,
                            const float* __restrict__ Wn,
                            const float* __restrict__ Wagn,
                            const float* __restrict__ Wnga,
                            const float* __restrict__ Wq,
                            WS* __restrict__ ws)
{
  const int t = threadIdx.x;
  const int b = blockIdx.x;
  if (b == 0) {
    __shared__ int s_off, s_max;
    if (t == 0) { s_off = 0; s_max = 0; }
    __syncthreads();
    int loc_off = 0, loc_max = 0;
    for (int i = t; i < 4096; i += 256) {
      int v = atm[i];
      loc_max = max(loc_max, v);
      if ((i & 3) != 0 && v != 0) loc_off = 1;
    }
    if (loc_off) atomicOr(&s_off, 1);
    atomicMax(&s_max, loc_max);
    __syncthreads();
    if (t == 0) ws->flag = (s_max > 1) ? 1 : (s_off ? 0 : 1);
  }
  for (int e = b * 256 + t; e < 112 * 256; e += 64 * 256) {
    int ro = e >> 8, k = e & 255;
    float w = 0.f;
    if (ro == 0)       w = Wn[k];
    else if (ro < 33)  w = Wagn[(ro - 1) * 256 + k];
    else if (ro < 65)  w = Wnga[(ro - 33) * 256 + k];
    else if (ro < 97)  w = 0.5f * (Wq[(ro - 65) * 256 + k] + Wq[(ro - 33) * 256 + k]);
    ws->Wall[e] = w;
  }
}

__global__ __launch_bounds__(256, 4) void policy_kernel(
    const int* __restrict__ a_in,
    const float* __restrict__ values,
    const void* __restrict__ atm,
    const void* __restrict__ aam,
    const WS* __restrict__ ws,
    float* __restrict__ out)
{
  // Phase A: Vbuf double-buffer = float4[2][512] = 16 KB at sm[0..4095].
  // Phase B aliases: Out[97][65] = sm[0..6304], then pn/papt/pa/segq/hn.
  __shared__ float sm[6724];
  float4* vb4 = (float4*)sm;

  const int t  = threadIdx.x;
  const int g  = blockIdx.x;
  const int wv = t >> 6;
  const int n  = t & 63;                                  // this lane's node
  const int wvu = __builtin_amdgcn_readfirstlane(wv);     // wave-uniform row group
  const int vswz = n & 7;

  const float* vsrc = values + (size_t)g * 16384;

  // stage chunk kt2 (32 k-elems) into buffer b; dest slot f=(n_,k4s) holds
  // V[n_][kt2*32 + ((k4s^(n_&7))<<2) ..+3]  (inverse-swizzled source, linear dest)
  auto stage = [&](int kt2, int b) {
    #pragma unroll
    for (int i = 0; i < 2; ++i) {
      int f = (i << 8) + t;
      int n_ = f >> 3, k4s = f & 7;
      const float* src = vsrc + n_ * 256 + (kt2 << 5) + ((k4s ^ (n_ & 7)) << 2);
      l_void* dst = (l_void*)(vb4 + (b << 9) + (i << 8) + (wv << 6));
      __builtin_amdgcn_global_load_lds((g_void*)src, dst, 16, 0, 0);
    }
  };

  const int rbase = wvu ? wvu * 24 + 1 : 0;   // rows: 0-24 | 25-48 | 49-72 | 73-96
  const int rcnt  = wvu ? 24 : 25;

  float acc[25];
  #pragma unroll
  for (int r = 0; r < 25; ++r) acc[r] = 0.f;

  stage(0, 0);
  __syncthreads();

  for (int kt = 0; kt < 8; ++kt) {
    if (kt < 7) stage(kt + 1, (kt + 1) & 1);
    // this lane's node-row fragment for this chunk (8 x b128, conflict-free via swizzle)
    float4 vf[8];
    const float4* vb = vb4 + ((kt & 1) << 9) + (n << 3);
    #pragma unroll
    for (int k4 = 0; k4 < 8; ++k4) vf[k4] = vb[k4 ^ vswz];
    // rows via wave-uniform scalar loads of W (L2-resident, no VGPR cost)
    const float* wk = ws->Wall + (kt << 5);
    #pragma unroll
    for (int r = 0; r < 25; ++r) {
      if (r < rcnt) {
        const float* wr = wk + (rbase + r) * 256;
        float s = acc[r];
        #pragma unroll
        for (int k4 = 0; k4 < 8; ++k4) {
          s = fmaf(vf[k4].x, wr[(k4 << 2) + 0], s);
          s = fmaf(vf[k4].y, wr[(k4 << 2) + 1], s);
          s = fmaf(vf[k4].z, wr[(k4 << 2) + 2], s);
          s = fmaf(vf[k4].w, wr[(k4 << 2) + 3], s);
        }
        acc[r] = s;
      }
    }
    __syncthreads();  // stage(kt+1) drained + all reads of buf(kt&1) done
  }

  // ---- write logits to Out[row][node] (stride 65; consecutive lanes = free) ----
  float* Out = sm;
  #pragma unroll
  for (int r = 0; r < 25; ++r)
    if (r < rcnt) Out[(rbase + r) * 65 + n] = acc[r];
  __syncthreads();

  float* pn   = sm + 6308;  // 64
  float* papt = sm + 6372;  // 8*32
  float* pa   = sm + 6628;  // 32
  float* segq = sm + 6660;  // 32
  float* hn   = sm + 6692;  // 32

  const int f4 = ws->flag;
  const size_t mb = (size_t)g * 2048;
  auto mget = [&](const void* p, size_t idx) -> bool {
    return f4 ? (((const int*)p)[idx] != 0)
              : (((const unsigned char*)p)[idx] != 0);
  };

  // ---- B1: p_n = softmax over 64 node logits (wave 0) ----
  if (t < 64) {
    float x = Out[t];
    float m = x;
    #pragma unroll
    for (int s = 32; s > 0; s >>= 1) m = fmaxf(m, __shfl_xor(m, s));
    float z = __expf(x - m);
    float su = z;
    #pragma unroll
    for (int s = 32; s > 0; s >>= 1) su += __shfl_xor(su, s);
    pn[t] = z / su;
  }
  __syncthreads();

  // ---- B2: p_a_given_n row softmax (32-lane groups), accumulate p_a partials ----
  {
    const int aA = t & 31, grp = t >> 5;
    float part = 0.f;
    for (int j = 0; j < 8; ++j) {
      int nn = grp * 8 + j;
      bool mk = mget(atm, mb + (size_t)nn * 32 + aA);
      float l = mk ? Out[(1 + aA) * 65 + nn] : NEGV;
      float m = l;
      #pragma unroll
      for (int s = 16; s > 0; s >>= 1) m = fmaxf(m, __shfl_xor(m, s));
      float z = __expf(l - m);
      float su = z;
      #pragma unroll
      for (int s = 16; s > 0; s >>= 1) su += __shfl_xor(su, s);
      part += pn[nn] * (z / su);
    }
    papt[grp * 32 + aA] = part;
  }

  // ---- B3: p_n__a segment softmax per action column (8-lane groups x 8 nodes) ----
  {
    const int a2 = t >> 3, r = t & 7;
    float lj[8];
    float m = -3.4e38f;
    #pragma unroll
    for (int j = 0; j < 8; ++j) {
      int nn = r * 8 + j;
      size_t mi = mb + (size_t)nn * 32 + a2;
      bool mk = mget(atm, mi) && mget(aam, mi);
      float l = mk ? Out[(33 + a2) * 65 + nn] : NEGV;
      lj[j] = l;
      m = fmaxf(m, l);
    }
    #pragma unroll
    for (int s = 4; s > 0; s >>= 1) m = fmaxf(m, __shfl_xor(m, s));
    float su = 0.f;
    #pragma unroll
    for (int j = 0; j < 8; ++j) { lj[j] = __expf(lj[j] - m); su += lj[j]; }
    #pragma unroll
    for (int s = 4; s > 0; s >>= 1) su += __shfl_xor(su, s);
    float inv = 1.f / su;
    float hq = 0.f, pq = 0.f;
    #pragma unroll
    for (int j = 0; j < 8; ++j) {
      int nn = r * 8 + j;
      float p = lj[j] * inv;
      Out[(33 + a2) * 65 + nn] = p;                 // p_n__a in place
      hq -= p * __logf(p + EPSV);
      pq = fmaf(p, Out[(65 + a2) * 65 + nn], pq);   // q row
    }
    #pragma unroll
    for (int s = 4; s > 0; s >>= 1) { hq += __shfl_xor(hq, s); pq += __shfl_xor(pq, s); }
    if (r == 0) { segq[a2] = pq; hn[a2] = hq; }
  }
  __syncthreads();

  // ---- B4: finalize ----
  if (t < 32) {
    float s0 = 0.f;
    #pragma unroll
    for (int gq = 0; gq < 8; ++gq) s0 += papt[gq * 32 + t];
    pa[t] = s0;
    out[6144 + g * 32 + t] = s0;  // p_a
    float v1 = s0 * segq[t];
    float e1 = -s0 * __logf(s0 + EPSV);
    float e2 = s0 * hn[t];
    #pragma unroll
    for (int s = 16; s > 0; s >>= 1) {
      v1 += __shfl_xor(v1, s);
      e1 += __shfl_xor(e1, s);
      e2 += __shfl_xor(e2, s);
    }
    if (t == 0) {
      out[4096 + g] = v1;       // value
      out[2048 + g] = e1 + e2;  // entropy
      int act = a_in[g * 2 + 0];
      int anl = a_in[g * 2 + 1] - g * 64;
      out[g] = __logf(pa[act] + EPSV) + __logf(Out[(33 + act) * 65 + anl] + EPSV);
    }
  }
  const size_t ob = 71680 + (size_t)g * 2048;
  #pragma unroll
  for (int i = 0; i < 8; ++i) {
    int e = t + (i << 8);
    out[ob + e] = Out[(33 + (e & 31)) * 65 + (e >> 5)];
  }
}

extern "C" void kernel_launch(void* const* d_in, const int* in_sizes, int n_in,
                              void* d_out, int out_size, void* d_ws, size_t ws_size,
                              hipStream_t stream)
{
  const int*   a_in   = (const int*)d_in[0];
  const float* values = (const float*)d_in[1];
  const void*  atm    = d_in[3];
  const void*  aam    = d_in[4];
  const float* Wn     = (const float*)d_in[6];
  const float* Wagn   = (const float*)d_in[7];
  const float* Wnga   = (const float*)d_in[8];
  const float* Wq     = (const float*)d_in[9];
  WS*    ws  = (WS*)d_ws;
  float* out = (float*)d_out;

  hipLaunchKernelGGL(prep_kernel, dim3(64), dim3(256), 0, stream,
                     (const unsigned char*)atm, Wn, Wagn, Wnga, Wq, ws);
  hipLaunchKernelGGL(policy_kernel, dim3(NG), dim3(256), 0, stream,
                     a_in, values, atm, aam, ws, out);
}

// Round 5
// 346.201 us; speedup vs baseline: 2.4933x; 1.0636x over previous
//
#include <hip/hip_runtime.h>

// ActionThenNodePolicy — MI355X fp32, round 5.
// 1 block (256 thr) per graph. Lane = node; wave = row-group (25/24/24/24 of 97).
// Phase A: NO LDS, NO barriers — V loaded per-lane into VGPRs (double-buffered),
// W via wave-uniform s_load from chunk-transposed layout [kt][112][32]
// (14 KB/chunk -> scalar-cache resident). Phase B: in-block softmaxes in LDS.

#define NG   2048
#define NEGV -1000000000.0f
#define EPSV 1e-20f

struct WS {
  int flag;          // 1 => mask elements are 4-byte, 0 => 1-byte bool
  int pad[63];
  float Wall[8 * 112 * 32]; // [kt][row][kk]; rows: 0 W_node, 1..32 W_agn, 33..64 W_nga, 65..96 q
};

__global__ void prep_kernel(const unsigned char* __restrict__ atm,
                            const float* __restrict__ Wn,
                            const float* __restrict__ Wagn,
                            const float* __restrict__ Wnga,
                            const float* __restrict__ Wq,
                            WS* __restrict__ ws)
{
  const int t = threadIdx.x;
  const int b = blockIdx.x;
  if (b == 0) {
    __shared__ int s_off, s_max;
    if (t == 0) { s_off = 0; s_max = 0; }
    __syncthreads();
    int loc_off = 0, loc_max = 0;
    for (int i = t; i < 4096; i += 256) {
      int v = atm[i];
      loc_max = max(loc_max, v);
      if ((i & 3) != 0 && v != 0) loc_off = 1;
    }
    if (loc_off) atomicOr(&s_off, 1);
    atomicMax(&s_max, loc_max);
    __syncthreads();
    if (t == 0) ws->flag = (s_max > 1) ? 1 : (s_off ? 0 : 1);
  }
  for (int e = b * 256 + t; e < 112 * 256; e += 64 * 256) {
    int ro = e >> 8, k = e & 255;
    float w = 0.f;
    if (ro == 0)       w = Wn[k];
    else if (ro < 33)  w = Wagn[(ro - 1) * 256 + k];
    else if (ro < 65)  w = Wnga[(ro - 33) * 256 + k];
    else if (ro < 97)  w = 0.5f * (Wq[(ro - 65) * 256 + k] + Wq[(ro - 33) * 256 + k]);
    ws->Wall[(k >> 5) * 3584 + ro * 32 + (k & 31)] = w;
  }
}

__device__ __forceinline__ void load_chunk(float4 (&vX)[8], const float4* __restrict__ vrow) {
  #pragma unroll
  for (int k4 = 0; k4 < 8; ++k4) vX[k4] = vrow[k4];
}

__device__ __forceinline__ void compute_chunk(const float4 (&vX)[8],
                                              const float* __restrict__ wt,
                                              float (&acc)[25], int rcnt) {
  #pragma unroll
  for (int r = 0; r < 25; ++r) {
    if (r < rcnt) {
      const float* wr = wt + r * 32;
      float s = acc[r];
      #pragma unroll
      for (int k4 = 0; k4 < 8; ++k4) {
        s = fmaf(vX[k4].x, wr[(k4 << 2) + 0], s);
        s = fmaf(vX[k4].y, wr[(k4 << 2) + 1], s);
        s = fmaf(vX[k4].z, wr[(k4 << 2) + 2], s);
        s = fmaf(vX[k4].w, wr[(k4 << 2) + 3], s);
      }
      acc[r] = s;
    }
  }
}

__global__ __launch_bounds__(256, 4) void policy_kernel(
    const int* __restrict__ a_in,
    const float* __restrict__ values,
    const void* __restrict__ atm,
    const void* __restrict__ aam,
    const WS* __restrict__ ws,
    float* __restrict__ out)
{
  // LDS: Out[97][65] + pn/papt/pa/segq/hn = 6724 floats = 26.9 KB.
  __shared__ float sm[6724];

  const int t  = threadIdx.x;
  const int g  = blockIdx.x;
  const int n  = t & 63;                                        // lane's node
  const int wvu = __builtin_amdgcn_readfirstlane(t >> 6);       // wave-uniform group
  const int rbase = wvu ? wvu * 24 + 1 : 0;                     // 0-24 | 25-48 | 49-72 | 73-96
  const int rcnt  = wvu ? 24 : 25;

  float acc[25];
  #pragma unroll
  for (int r = 0; r < 25; ++r) acc[r] = 0.f;

  const float4* vrow = (const float4*)(values + (size_t)g * 16384 + (size_t)n * 256);
  const float*  wbase = ws->Wall + rbase * 32;

  float4 vA[8], vB[8];
  load_chunk(vA, vrow);           // chunk 0

  #pragma unroll 1
  for (int kt = 0; kt < 8; kt += 2) {
    load_chunk(vB, vrow + (kt + 1) * 8);            // prefetch odd chunk
    compute_chunk(vA, wbase + kt * 3584, acc, rcnt);
    if (kt < 6) load_chunk(vA, vrow + (kt + 2) * 8); // prefetch next even chunk
    compute_chunk(vB, wbase + (kt + 1) * 3584, acc, rcnt);
  }

  // ---- write logits to Out[row][node] ----
  float* Out = sm;
  #pragma unroll
  for (int r = 0; r < 25; ++r)
    if (r < rcnt) Out[(rbase + r) * 65 + n] = acc[r];
  __syncthreads();

  float* pn   = sm + 6308;  // 64
  float* papt = sm + 6372;  // 8*32
  float* pa   = sm + 6628;  // 32
  float* segq = sm + 6660;  // 32
  float* hn   = sm + 6692;  // 32

  const int f4 = ws->flag;
  const size_t mb = (size_t)g * 2048;
  auto mget = [&](const void* p, size_t idx) -> bool {
    return f4 ? (((const int*)p)[idx] != 0)
              : (((const unsigned char*)p)[idx] != 0);
  };

  // ---- B1: p_n = softmax over 64 node logits (wave 0) ----
  if (t < 64) {
    float x = Out[t];
    float m = x;
    #pragma unroll
    for (int s = 32; s > 0; s >>= 1) m = fmaxf(m, __shfl_xor(m, s));
    float z = __expf(x - m);
    float su = z;
    #pragma unroll
    for (int s = 32; s > 0; s >>= 1) su += __shfl_xor(su, s);
    pn[t] = z / su;
  }
  __syncthreads();

  // ---- B2: p_a_given_n row softmax (32-lane groups), accumulate p_a partials ----
  {
    const int aA = t & 31, grp = t >> 5;
    float part = 0.f;
    for (int j = 0; j < 8; ++j) {
      int nn = grp * 8 + j;
      bool mk = mget(atm, mb + (size_t)nn * 32 + aA);
      float l = mk ? Out[(1 + aA) * 65 + nn] : NEGV;
      float m = l;
      #pragma unroll
      for (int s = 16; s > 0; s >>= 1) m = fmaxf(m, __shfl_xor(m, s));
      float z = __expf(l - m);
      float su = z;
      #pragma unroll
      for (int s = 16; s > 0; s >>= 1) su += __shfl_xor(su, s);
      part += pn[nn] * (z / su);
    }
    papt[grp * 32 + aA] = part;
  }

  // ---- B3: p_n__a segment softmax per action column (8-lane groups x 8 nodes) ----
  {
    const int a2 = t >> 3, r = t & 7;
    float lj[8];
    float m = -3.4e38f;
    #pragma unroll
    for (int j = 0; j < 8; ++j) {
      int nn = r * 8 + j;
      size_t mi = mb + (size_t)nn * 32 + a2;
      bool mk = mget(atm, mi) && mget(aam, mi);
      float l = mk ? Out[(33 + a2) * 65 + nn] : NEGV;
      lj[j] = l;
      m = fmaxf(m, l);
    }
    #pragma unroll
    for (int s = 4; s > 0; s >>= 1) m = fmaxf(m, __shfl_xor(m, s));
    float su = 0.f;
    #pragma unroll
    for (int j = 0; j < 8; ++j) { lj[j] = __expf(lj[j] - m); su += lj[j]; }
    #pragma unroll
    for (int s = 4; s > 0; s >>= 1) su += __shfl_xor(su, s);
    float inv = 1.f / su;
    float hq = 0.f, pq = 0.f;
    #pragma unroll
    for (int j = 0; j < 8; ++j) {
      int nn = r * 8 + j;
      float p = lj[j] * inv;
      Out[(33 + a2) * 65 + nn] = p;                 // p_n__a in place
      hq -= p * __logf(p + EPSV);
      pq = fmaf(p, Out[(65 + a2) * 65 + nn], pq);   // q row
    }
    #pragma unroll
    for (int s = 4; s > 0; s >>= 1) { hq += __shfl_xor(hq, s); pq += __shfl_xor(pq, s); }
    if (r == 0) { segq[a2] = pq; hn[a2] = hq; }
  }
  __syncthreads();

  // ---- B4: finalize ----
  if (t < 32) {
    float s0 = 0.f;
    #pragma unroll
    for (int gq = 0; gq < 8; ++gq) s0 += papt[gq * 32 + t];
    pa[t] = s0;
    out[6144 + g * 32 + t] = s0;  // p_a
    float v1 = s0 * segq[t];
    float e1 = -s0 * __logf(s0 + EPSV);
    float e2 = s0 * hn[t];
    #pragma unroll
    for (int s = 16; s > 0; s >>= 1) {
      v1 += __shfl_xor(v1, s);
      e1 += __shfl_xor(e1, s);
      e2 += __shfl_xor(e2, s);
    }
    if (t == 0) {
      out[4096 + g] = v1;       // value
      out[2048 + g] = e1 + e2;  // entropy
      int act = a_in[g * 2 + 0];
      int anl = a_in[g * 2 + 1] - g * 64;
      out[g] = __logf(pa[act] + EPSV) + __logf(Out[(33 + act) * 65 + anl] + EPSV);
    }
  }
  const size_t ob = 71680 + (size_t)g * 2048;
  #pragma unroll
  for (int i = 0; i < 8; ++i) {
    int e = t + (i << 8);
    out[ob + e] = Out[(33 + (e & 31)) * 65 + (e >> 5)];
  }
}

extern "C" void kernel_launch(void* const* d_in, const int* in_sizes, int n_in,
                              void* d_out, int out_size, void* d_ws, size_t ws_size,
                              hipStream_t stream)
{
  const int*   a_in   = (const int*)d_in[0];
  const float* values = (const float*)d_in[1];
  const void*  atm    = d_in[3];
  const void*  aam    = d_in[4];
  const float* Wn     = (const float*)d_in[6];
  const float* Wagn   = (const float*)d_in[7];
  const float* Wnga   = (const float*)d_in[8];
  const float* Wq     = (const float*)d_in[9];
  WS*    ws  = (WS*)d_ws;
  float* out = (float*)d_out;

  hipLaunchKernelGGL(prep_kernel, dim3(64), dim3(256), 0, stream,
                     (const unsigned char*)atm, Wn, Wagn, Wnga, Wq, ws);
  hipLaunchKernelGGL(policy_kernel, dim3(NG), dim3(256), 0, stream,
                     a_in, values, atm, aam, ws, out);
}

// Round 6
// 289.695 us; speedup vs baseline: 2.9797x; 1.1951x over previous
//
#include <hip/hip_runtime.h>

// ActionThenNodePolicy — MI355X, round 6: split-bf16 MFMA phase A.
// 1 block (256 thr) per graph. Wave w = node-tile nt (16 nodes); 7 M-tiles of
// W rows (112 padded, 97 real). A (W) fragments pre-arranged by prep into the
// exact per-lane MFMA layout -> contiguous 1KB wave loads, no LDS, no s_load.
// B (V) fragments read directly from global (2 dwordx4/wave/kb, fully
// coalesced), split to bf16 hi/lo in-register. 3 MFMAs (hh, hl, lh) per tile
// per kb recover ~fp32 accuracy. Phase B: in-block softmaxes (unchanged).

#define NG   2048
#define NEGV -1000000000.0f
#define EPSV 1e-20f

typedef __attribute__((ext_vector_type(8))) short bf16x8;
typedef __attribute__((ext_vector_type(4))) float f32x4;
typedef __attribute__((ext_vector_type(4))) unsigned int u32x4;

struct WS {
  int flag;          // 1 => mask elements are 4-byte, 0 => 1-byte bool
  int pad[63];
  unsigned short Ahi[8 * 7 * 64 * 8]; // [kb][mt][lane][j] bf16 hi
  unsigned short Alo[8 * 7 * 64 * 8]; // [kb][mt][lane][j] bf16 lo
};

__global__ void prep_kernel(const unsigned char* __restrict__ atm,
                            const float* __restrict__ Wn,
                            const float* __restrict__ Wagn,
                            const float* __restrict__ Wnga,
                            const float* __restrict__ Wq,
                            WS* __restrict__ ws)
{
  const int t = threadIdx.x;
  const int b = blockIdx.x;
  if (b == 0) {
    __shared__ int s_off, s_max;
    if (t == 0) { s_off = 0; s_max = 0; }
    __syncthreads();
    int loc_off = 0, loc_max = 0;
    for (int i = t; i < 4096; i += 256) {
      int v = atm[i];
      loc_max = max(loc_max, v);
      if ((i & 3) != 0 && v != 0) loc_off = 1;
    }
    if (loc_off) atomicOr(&s_off, 1);
    atomicMax(&s_max, loc_max);
    __syncthreads();
    if (t == 0) ws->flag = (s_max > 1) ? 1 : (s_off ? 0 : 1);
  }
  // Build pre-fragmented W (hi/lo bf16). Element e -> (kb, mt, lane, j):
  // row = mt*16 + (lane&15); k = kb*32 + 4*(lane>>4) + (j&3) + 16*(j>>2).
  for (int e = b * 256 + t; e < 28672; e += 64 * 256) {
    int kb  = e / 3584;
    int rem = e - kb * 3584;
    int mt  = rem >> 9;
    int le  = rem & 511;
    int lane = le >> 3, j = le & 7;
    int row = mt * 16 + (lane & 15);
    int k   = kb * 32 + ((lane >> 4) << 2) + (j & 3) + ((j >> 2) << 4);
    float w = 0.f;
    if (row == 0)       w = Wn[k];
    else if (row < 33)  w = Wagn[(row - 1) * 256 + k];
    else if (row < 65)  w = Wnga[(row - 33) * 256 + k];
    else if (row < 97)  w = 0.5f * (Wq[(row - 65) * 256 + k] + Wq[(row - 33) * 256 + k]);
    unsigned int ub = __float_as_uint(w);
    unsigned short hi = (unsigned short)(ub >> 16);
    float lof = w - __uint_as_float(ub & 0xFFFF0000u);
    unsigned short lo = (unsigned short)(__float_as_uint(lof) >> 16);
    ws->Ahi[e] = hi;
    ws->Alo[e] = lo;
  }
}

__device__ __forceinline__ void split_bf16(const float4& fa, const float4& fb,
                                           bf16x8& bh, bf16x8& bl)
{
  unsigned int ax = __float_as_uint(fa.x), ay = __float_as_uint(fa.y);
  unsigned int az = __float_as_uint(fa.z), aw = __float_as_uint(fa.w);
  unsigned int bx = __float_as_uint(fb.x), by = __float_as_uint(fb.y);
  unsigned int bz = __float_as_uint(fb.z), bw = __float_as_uint(fb.w);
  u32x4 H;
  H.x = (ax >> 16) | (ay & 0xFFFF0000u);
  H.y = (az >> 16) | (aw & 0xFFFF0000u);
  H.z = (bx >> 16) | (by & 0xFFFF0000u);
  H.w = (bz >> 16) | (bw & 0xFFFF0000u);
  float lax = fa.x - __uint_as_float(ax & 0xFFFF0000u);
  float lay = fa.y - __uint_as_float(ay & 0xFFFF0000u);
  float laz = fa.z - __uint_as_float(az & 0xFFFF0000u);
  float law = fa.w - __uint_as_float(aw & 0xFFFF0000u);
  float lbx = fb.x - __uint_as_float(bx & 0xFFFF0000u);
  float lby = fb.y - __uint_as_float(by & 0xFFFF0000u);
  float lbz = fb.z - __uint_as_float(bz & 0xFFFF0000u);
  float lbw = fb.w - __uint_as_float(bw & 0xFFFF0000u);
  u32x4 L;
  L.x = (__float_as_uint(lax) >> 16) | (__float_as_uint(lay) & 0xFFFF0000u);
  L.y = (__float_as_uint(laz) >> 16) | (__float_as_uint(law) & 0xFFFF0000u);
  L.z = (__float_as_uint(lbx) >> 16) | (__float_as_uint(lby) & 0xFFFF0000u);
  L.w = (__float_as_uint(lbz) >> 16) | (__float_as_uint(lbw) & 0xFFFF0000u);
  bh = __builtin_bit_cast(bf16x8, H);
  bl = __builtin_bit_cast(bf16x8, L);
}

__global__ __launch_bounds__(256, 4) void policy_kernel(
    const int* __restrict__ a_in,
    const float* __restrict__ values,
    const void* __restrict__ atm,
    const void* __restrict__ aam,
    const WS* __restrict__ ws,
    float* __restrict__ out)
{
  // LDS: Out[97][65] + pn/papt/pa/segq/hn = 6724 floats = 26.9 KB.
  __shared__ float sm[6724];

  const int t  = threadIdx.x;
  const int g  = blockIdx.x;
  const int l  = t & 63;
  const int nt = __builtin_amdgcn_readfirstlane(t >> 6);  // wave = node tile
  const int col = l & 15;    // node within tile / M within tile (C/D col)
  const int h   = l >> 4;    // k-group

  f32x4 acc[7];
  #pragma unroll
  for (int mt = 0; mt < 7; ++mt) acc[mt] = f32x4{0.f, 0.f, 0.f, 0.f};

  const float4* vbase = (const float4*)(values + (size_t)g * 16384 +
                                        (size_t)(nt * 16 + col) * 256);
  const u32x4* Ah = (const u32x4*)ws->Ahi;
  const u32x4* Al = (const u32x4*)ws->Alo;

  auto compute = [&](int kb, const float4& fa, const float4& fb) {
    bf16x8 bh, bl;
    split_bf16(fa, fb, bh, bl);
    #pragma unroll
    for (int mt = 0; mt < 7; ++mt) {
      int idx = (kb * 7 + mt) * 64 + l;
      bf16x8 ah = __builtin_bit_cast(bf16x8, Ah[idx]);
      bf16x8 al = __builtin_bit_cast(bf16x8, Al[idx]);
      acc[mt] = __builtin_amdgcn_mfma_f32_16x16x32_bf16(ah, bh, acc[mt], 0, 0, 0);
      acc[mt] = __builtin_amdgcn_mfma_f32_16x16x32_bf16(ah, bl, acc[mt], 0, 0, 0);
      acc[mt] = __builtin_amdgcn_mfma_f32_16x16x32_bf16(al, bh, acc[mt], 0, 0, 0);
    }
  };

  // fa = float4 #(kb*8 + h) of this lane's node row (k = kb*32 + 4h .. +3)
  // fb = float4 #(kb*8 + 4 + h)                    (k = kb*32 + 16 + 4h ..)
  float4 fa0 = vbase[h], fb0 = vbase[4 + h];
  #pragma unroll 1
  for (int kb = 0; kb < 8; kb += 2) {
    float4 fa1 = vbase[(kb + 1) * 8 + h];
    float4 fb1 = vbase[(kb + 1) * 8 + 4 + h];
    compute(kb, fa0, fb0);
    if (kb < 6) {
      fa0 = vbase[(kb + 2) * 8 + h];
      fb0 = vbase[(kb + 2) * 8 + 4 + h];
    }
    compute(kb + 1, fa1, fb1);
  }

  // ---- write logits: C/D layout col=lane&15 (node), row=4*(l>>4)+reg ----
  float* Out = sm;
  #pragma unroll
  for (int mt = 0; mt < 7; ++mt) {
    #pragma unroll
    for (int r = 0; r < 4; ++r) {
      int row = mt * 16 + h * 4 + r;
      if (row < 97) Out[row * 65 + nt * 16 + col] = acc[mt][r];
    }
  }
  __syncthreads();

  float* pn   = sm + 6308;  // 64
  float* papt = sm + 6372;  // 8*32
  float* pa   = sm + 6628;  // 32
  float* segq = sm + 6660;  // 32
  float* hn   = sm + 6692;  // 32

  const int f4 = ws->flag;
  const size_t mb = (size_t)g * 2048;
  auto mget = [&](const void* p, size_t idx) -> bool {
    return f4 ? (((const int*)p)[idx] != 0)
              : (((const unsigned char*)p)[idx] != 0);
  };

  // ---- B1: p_n = softmax over 64 node logits (wave 0) ----
  if (t < 64) {
    float x = Out[t];
    float m = x;
    #pragma unroll
    for (int s = 32; s > 0; s >>= 1) m = fmaxf(m, __shfl_xor(m, s));
    float z = __expf(x - m);
    float su = z;
    #pragma unroll
    for (int s = 32; s > 0; s >>= 1) su += __shfl_xor(su, s);
    pn[t] = z / su;
  }
  __syncthreads();

  // ---- B2: p_a_given_n row softmax (32-lane groups), accumulate p_a partials ----
  {
    const int aA = t & 31, grp = t >> 5;
    float part = 0.f;
    for (int j = 0; j < 8; ++j) {
      int nn = grp * 8 + j;
      bool mk = mget(atm, mb + (size_t)nn * 32 + aA);
      float l2 = mk ? Out[(1 + aA) * 65 + nn] : NEGV;
      float m = l2;
      #pragma unroll
      for (int s = 16; s > 0; s >>= 1) m = fmaxf(m, __shfl_xor(m, s));
      float z = __expf(l2 - m);
      float su = z;
      #pragma unroll
      for (int s = 16; s > 0; s >>= 1) su += __shfl_xor(su, s);
      part += pn[nn] * (z / su);
    }
    papt[grp * 32 + aA] = part;
  }

  // ---- B3: p_n__a segment softmax per action column (8-lane groups x 8 nodes) ----
  {
    const int a2 = t >> 3, r = t & 7;
    float lj[8];
    float m = -3.4e38f;
    #pragma unroll
    for (int j = 0; j < 8; ++j) {
      int nn = r * 8 + j;
      size_t mi = mb + (size_t)nn * 32 + a2;
      bool mk = mget(atm, mi) && mget(aam, mi);
      float l2 = mk ? Out[(33 + a2) * 65 + nn] : NEGV;
      lj[j] = l2;
      m = fmaxf(m, l2);
    }
    #pragma unroll
    for (int s = 4; s > 0; s >>= 1) m = fmaxf(m, __shfl_xor(m, s));
    float su = 0.f;
    #pragma unroll
    for (int j = 0; j < 8; ++j) { lj[j] = __expf(lj[j] - m); su += lj[j]; }
    #pragma unroll
    for (int s = 4; s > 0; s >>= 1) su += __shfl_xor(su, s);
    float inv = 1.f / su;
    float hq = 0.f, pq = 0.f;
    #pragma unroll
    for (int j = 0; j < 8; ++j) {
      int nn = r * 8 + j;
      float p = lj[j] * inv;
      Out[(33 + a2) * 65 + nn] = p;                 // p_n__a in place
      hq -= p * __logf(p + EPSV);
      pq = fmaf(p, Out[(65 + a2) * 65 + nn], pq);   // q row
    }
    #pragma unroll
    for (int s = 4; s > 0; s >>= 1) { hq += __shfl_xor(hq, s); pq += __shfl_xor(pq, s); }
    if (r == 0) { segq[a2] = pq; hn[a2] = hq; }
  }
  __syncthreads();

  // ---- B4: finalize ----
  if (t < 32) {
    float s0 = 0.f;
    #pragma unroll
    for (int gq = 0; gq < 8; ++gq) s0 += papt[gq * 32 + t];
    pa[t] = s0;
    out[6144 + g * 32 + t] = s0;  // p_a
    float v1 = s0 * segq[t];
    float e1 = -s0 * __logf(s0 + EPSV);
    float e2 = s0 * hn[t];
    #pragma unroll
    for (int s = 16; s > 0; s >>= 1) {
      v1 += __shfl_xor(v1, s);
      e1 += __shfl_xor(e1, s);
      e2 += __shfl_xor(e2, s);
    }
    if (t == 0) {
      out[4096 + g] = v1;       // value
      out[2048 + g] = e1 + e2;  // entropy
      int act = a_in[g * 2 + 0];
      int anl = a_in[g * 2 + 1] - g * 64;
      out[g] = __logf(pa[act] + EPSV) + __logf(Out[(33 + act) * 65 + anl] + EPSV);
    }
  }
  const size_t ob = 71680 + (size_t)g * 2048;
  #pragma unroll
  for (int i = 0; i < 8; ++i) {
    int e = t + (i << 8);
    out[ob + e] = Out[(33 + (e & 31)) * 65 + (e >> 5)];
  }
}

extern "C" void kernel_launch(void* const* d_in, const int* in_sizes, int n_in,
                              void* d_out, int out_size, void* d_ws, size_t ws_size,
                              hipStream_t stream)
{
  const int*   a_in   = (const int*)d_in[0];
  const float* values = (const float*)d_in[1];
  const void*  atm    = d_in[3];
  const void*  aam    = d_in[4];
  const float* Wn     = (const float*)d_in[6];
  const float* Wagn   = (const float*)d_in[7];
  const float* Wnga   = (const float*)d_in[8];
  const float* Wq     = (const float*)d_in[9];
  WS*    ws  = (WS*)d_ws;
  float* out = (float*)d_out;

  hipLaunchKernelGGL(prep_kernel, dim3(64), dim3(256), 0, stream,
                     (const unsigned char*)atm, Wn, Wagn, Wnga, Wq, ws);
  hipLaunchKernelGGL(policy_kernel, dim3(NG), dim3(256), 0, stream,
                     a_in, values, atm, aam, ws, out);
}